// Round 13
// baseline (34250.031 us; speedup 1.0000x reference)
//
#include <hip/hip_runtime.h>

#define TSEQ 2048
#define NB   32
#define HIDN 256
#define NG   1024   // 4*HID
#define NCH_R 45    // weight chunks pinned in VGPRs (180 regs)
#define NCH_L 19    // weight chunks in LDS (152 KB)

typedef _Float16 half_t;
typedef _Float16 half2_t __attribute__((ext_vector_type(2)));

__device__ __forceinline__ float fdot2f16(unsigned int a, unsigned int b, float c) {
#if __has_builtin(__builtin_amdgcn_fdot2)
    return __builtin_amdgcn_fdot2(__builtin_bit_cast(half2_t, a),
                                  __builtin_bit_cast(half2_t, b), c, false);
#else
    half2_t x = __builtin_bit_cast(half2_t, a);
    half2_t y = __builtin_bit_cast(half2_t, b);
    return c + (float)x[0] * (float)y[0] + (float)x[1] * (float)y[1];
#endif
}

__device__ __forceinline__ unsigned int packh2(float lo, float hi) {
    half_t l = (half_t)lo, h = (half_t)hi;
    return (unsigned int)__builtin_bit_cast(unsigned short, l) |
           ((unsigned int)__builtin_bit_cast(unsigned short, h) << 16);
}

__device__ __forceinline__ float fast_exp2(float x) {
#if __has_builtin(__builtin_amdgcn_exp2f)
    return __builtin_amdgcn_exp2f(x);
#else
    return exp2f(x);
#endif
}
__device__ __forceinline__ float fast_rcp(float x) {
#if __has_builtin(__builtin_amdgcn_rcpf)
    return __builtin_amdgcn_rcpf(x);
#else
    return 1.0f / x;
#endif
}

__device__ __forceinline__ float sigf(float x) {
    float e = fast_exp2(x * -1.442695041f);
    return fast_rcp(1.0f + e);
}
__device__ __forceinline__ float tanh_fast(float x) {
    float e = fast_exp2(x * 2.885390082f);
    return 1.0f - 2.0f * fast_rcp(e + 1.0f);
}

// keep-alive: value becomes opaque -> compiler cannot rematerialize the load
__device__ __forceinline__ void pin4(uint4& v) {
    asm volatile("" : "+v"(v.x), "+v"(v.y), "+v"(v.z), "+v"(v.w));
}

// ---------------------------------------------------------------------------
// K1: pack weights.
//  Wh -> NEW 512-thread ownership: thread t (u=t&255, hf=t>>8) owns columns
//    ca=(2hf)*256+u, cb=(2hf+1)*256+u.  64 chunks per thread: r_all<32 ->
//    (ca, k=r_all); r_all>=32 -> (cb, k=r_all-32).  Chunk kk of cb: kk<13 ->
//    WhpR[(32+kk)*512+t]; kk>=13 -> WhpL[(kk-13)*512+t].  ca chunks ->
//    WhpR[r_all*512+t].  uint4 comp d packs rows k*8+2d, k*8+2d+1 of col.
//  Wi -> Wip (xproj_gemm layout, unchanged).
// ---------------------------------------------------------------------------
__global__ void pack_w(const float* __restrict__ Wi, const float* __restrict__ Wh,
                       uint4* __restrict__ WhpR, uint4* __restrict__ WhpL,
                       uint4* __restrict__ Wip) {
    int idx = blockIdx.x * 256 + threadIdx.x;   // 0..65535
    if (idx < 32768) {
        int r_all = idx >> 9;          // 0..63
        int t = idx & 511;
        int u = t & 255, hf = t >> 8;
        int kk = r_all & 31;
        int col = ((r_all < 32) ? (2 * hf) : (2 * hf + 1)) * 256 + u;
        int k0 = kk * 8;
        uint4 v = make_uint4(
            packh2(Wh[(k0 + 0) * NG + col], Wh[(k0 + 1) * NG + col]),
            packh2(Wh[(k0 + 2) * NG + col], Wh[(k0 + 3) * NG + col]),
            packh2(Wh[(k0 + 4) * NG + col], Wh[(k0 + 5) * NG + col]),
            packh2(Wh[(k0 + 6) * NG + col], Wh[(k0 + 7) * NG + col]));
        if (r_all < 32)      WhpR[r_all * 512 + t] = v;
        else if (kk < 13)    WhpR[(32 + kk) * 512 + t] = v;
        else                 WhpL[(kk - 13) * 512 + t] = v;
    } else {
        int li = idx & 32767;
        int m4 = li >> 10, tt = li & 1023;
        int col = (tt & 3) * 256 + (tt >> 2);
        int k0 = m4 * 8;
        Wip[li] = make_uint4(
            packh2(Wi[(k0 + 0) * NG + col], Wi[(k0 + 1) * NG + col]),
            packh2(Wi[(k0 + 2) * NG + col], Wi[(k0 + 3) * NG + col]),
            packh2(Wi[(k0 + 4) * NG + col], Wi[(k0 + 5) * NG + col]),
            packh2(Wi[(k0 + 6) * NG + col], Wi[(k0 + 7) * NG + col]));
    }
}

// ---------------------------------------------------------------------------
// K2: x_proj GEMM (unchanged): X [65536][256] fp32 @ Wi -> XP ushort4,
// gate-interleaved f16: half index row*1024 + j*4 + g.
// ---------------------------------------------------------------------------
__global__ __launch_bounds__(1024) void xproj_gemm(
    const float* __restrict__ X, const uint4* __restrict__ Wip,
    ushort4* __restrict__ XP)
{
    __shared__ uint4 atile[32][32];
    const int tid = threadIdx.x;
    const long row0 = (long)blockIdx.x * 32;

    {
        int r = tid >> 5, kc = tid & 31;
        const float4* src = (const float4*)(X + (row0 + r) * 256 + kc * 8);
        float4 f0 = src[0], f1 = src[1];
        atile[r][kc] = make_uint4(packh2(f0.x, f0.y), packh2(f0.z, f0.w),
                                  packh2(f1.x, f1.y), packh2(f1.z, f1.w));
    }
    __syncthreads();

    const int j = tid & 255, rq = tid >> 8;
    float acc[8][4];
#pragma unroll
    for (int r = 0; r < 8; ++r)
#pragma unroll
        for (int g = 0; g < 4; ++g) acc[r][g] = 0.f;

    unsigned off = (unsigned)(j * 4);
#pragma unroll 2
    for (int m4 = 0; m4 < 32; ++m4) {
        uint4 w0 = Wip[off + 0];
        uint4 w1 = Wip[off + 1];
        uint4 w2 = Wip[off + 2];
        uint4 w3 = Wip[off + 3];
#pragma unroll
        for (int rr = 0; rr < 8; ++rr) {
            uint4 av = atile[rq * 8 + rr][m4];
            acc[rr][0] = fdot2f16(w0.x, av.x, acc[rr][0]);
            acc[rr][0] = fdot2f16(w0.y, av.y, acc[rr][0]);
            acc[rr][0] = fdot2f16(w0.z, av.z, acc[rr][0]);
            acc[rr][0] = fdot2f16(w0.w, av.w, acc[rr][0]);
            acc[rr][1] = fdot2f16(w1.x, av.x, acc[rr][1]);
            acc[rr][1] = fdot2f16(w1.y, av.y, acc[rr][1]);
            acc[rr][1] = fdot2f16(w1.z, av.z, acc[rr][1]);
            acc[rr][1] = fdot2f16(w1.w, av.w, acc[rr][1]);
            acc[rr][2] = fdot2f16(w2.x, av.x, acc[rr][2]);
            acc[rr][2] = fdot2f16(w2.y, av.y, acc[rr][2]);
            acc[rr][2] = fdot2f16(w2.z, av.z, acc[rr][2]);
            acc[rr][2] = fdot2f16(w2.w, av.w, acc[rr][2]);
            acc[rr][3] = fdot2f16(w3.x, av.x, acc[rr][3]);
            acc[rr][3] = fdot2f16(w3.y, av.y, acc[rr][3]);
            acc[rr][3] = fdot2f16(w3.z, av.z, acc[rr][3]);
            acc[rr][3] = fdot2f16(w3.w, av.w, acc[rr][3]);
        }
        off += 1024;
    }

#pragma unroll
    for (int rr = 0; rr < 8; ++rr) {
        long row = row0 + rq * 8 + rr;
        XP[row * 256 + j] = make_ushort4(
            __builtin_bit_cast(unsigned short, (half_t)acc[rr][0]),
            __builtin_bit_cast(unsigned short, (half_t)acc[rr][1]),
            __builtin_bit_cast(unsigned short, (half_t)acc[rr][2]),
            __builtin_bit_cast(unsigned short, (half_t)acc[rr][3]));
    }
}

// ---------------------------------------------------------------------------
// K3: persistent recurrence, ALL weights on-CU.
// Round-12 evidence: under a 64-reg occupancy target the allocator defeats
// both launch_bounds and asm pinning (AGPR shuffling). Fix the INCENTIVE:
// amdgpu_waves_per_eu(2,2) -> min=max=2 waves/EU -> 256-VGPR budget with no
// occupancy payoff for remat. 512 threads/WG (8 waves = exactly 2/EU).
// Thread (half=tid>>8, u=tid&255) owns 2 gate-columns of unit u
// (half 0: i,f; half 1: g,o). Weights: 45 chunks pinned VGPR (180 regs) +
// 19 chunks LDS (152 KB) = all 512 KB on-CU; zero L2 weight re-stream.
// h: 32 uniform ds_read_b128 (broadcast). Gate exchange via LDS exch[256];
// 2 barriers/step. 4 accumulator chains for VALU latency cover.
// ---------------------------------------------------------------------------
__global__
__attribute__((amdgpu_flat_work_group_size(512, 512)))
__attribute__((amdgpu_waves_per_eu(2, 2)))
void lstm_rec(
    const uint4* __restrict__ WhpR, const uint4* __restrict__ WhpL,
    const unsigned short* __restrict__ XPh, const float* __restrict__ bias,
    const float* __restrict__ h0, const float* __restrict__ c0,
    float* __restrict__ out)
{
    __shared__ __align__(16) uint4 wlds[NCH_L][512];   // 152 KB
    __shared__ __align__(16) uint4 hpair[2][32];       // 2 x 256 f16
    __shared__ __align__(8)  float2 exch[256];         // (g,o) hand-off

    const int tid  = threadIdx.x;
    const int b    = blockIdx.x;
    const int u    = tid & 255;
    const int half = tid >> 8;

    uint4 wr[NCH_R];
#pragma unroll
    for (int r = 0; r < NCH_R; ++r) wr[r] = WhpR[r * 512 + tid];
#pragma unroll
    for (int r = 0; r < NCH_R; ++r) pin4(wr[r]);
#pragma unroll
    for (int c = 0; c < NCH_L; ++c) wlds[c][tid] = WhpL[c * 512 + tid];

    const float b0 = bias[(2 * half + 0) * 256 + u];
    const float b1 = bias[(2 * half + 1) * 256 + u];
    float c_state = (half == 0) ? c0[b * HIDN + u] : 0.f;
    if (half == 0) {
        ((unsigned short*)hpair[0])[u] =
            __builtin_bit_cast(unsigned short, (half_t)h0[b * HIDN + u]);
    }
    // xp for (gate 2*half, u) and (2*half+1, u): adjacent halves, one dword
    const char* xpbase = (const char*)(XPh + (long)b * TSEQ * NG)
                       + u * 8 + half * 4;
    float* ys = out + 2 * NB * HIDN + (long)b * TSEQ * HIDN;
    __syncthreads();

    int buf = 0;
    for (int step = 0; step < TSEQ; ++step) {
        unsigned xpw = *(const unsigned*)(xpbase + (long)step * 2048);
        float xpf0 = (float)__builtin_bit_cast(half_t, (unsigned short)(xpw & 0xffff));
        float xpf1 = (float)__builtin_bit_cast(half_t, (unsigned short)(xpw >> 16));

        const uint4* hv4 = hpair[buf];
        float z0a = 0.f, z0b = 0.f, z1a = 0.f, z1b = 0.f;
#pragma unroll
        for (int kk = 0; kk < 32; kk += 2) {
            uint4 hv0 = hv4[kk];
            uint4 hv1 = hv4[kk + 1];
            uint4 wa0 = wr[kk];
            uint4 wa1 = wr[kk + 1];
            uint4 wb0 = (kk < 13)     ? wr[32 + kk]     : wlds[kk - 13][tid];
            uint4 wb1 = (kk + 1 < 13) ? wr[33 + kk]     : wlds[kk - 12][tid];
            z0a = fdot2f16(wa0.x, hv0.x, z0a); z0a = fdot2f16(wa0.y, hv0.y, z0a);
            z0a = fdot2f16(wa0.z, hv0.z, z0a); z0a = fdot2f16(wa0.w, hv0.w, z0a);
            z1a = fdot2f16(wb0.x, hv0.x, z1a); z1a = fdot2f16(wb0.y, hv0.y, z1a);
            z1a = fdot2f16(wb0.z, hv0.z, z1a); z1a = fdot2f16(wb0.w, hv0.w, z1a);
            z0b = fdot2f16(wa1.x, hv1.x, z0b); z0b = fdot2f16(wa1.y, hv1.y, z0b);
            z0b = fdot2f16(wa1.z, hv1.z, z0b); z0b = fdot2f16(wa1.w, hv1.w, z0b);
            z1b = fdot2f16(wb1.x, hv1.x, z1b); z1b = fdot2f16(wb1.y, hv1.y, z1b);
            z1b = fdot2f16(wb1.z, hv1.z, z1b); z1b = fdot2f16(wb1.w, hv1.w, z1b);
        }
        float z0 = (z0a + z0b) + xpf0 + b0;
        float z1 = (z1a + z1b) + xpf1 + b1;

        float a0, a1;
        if (half == 0) { a0 = sigf(z0);      a1 = sigf(z1); }   // i, f
        else           { a0 = tanh_fast(z0); a1 = sigf(z1); }   // g, o

        if (half == 1) exch[u] = make_float2(a0, a1);
        __syncthreads();

        if (half == 0) {
            float2 go = exch[u];                 // (g, o)
            float cn = a1 * c_state + a0 * go.x; // f*c + i*g
            float hn = go.y * tanh_fast(cn);     // o*tanh(c)
            c_state = cn;
            ((unsigned short*)hpair[buf ^ 1])[u] =
                __builtin_bit_cast(unsigned short, (half_t)hn);
            ys[(long)step * HIDN + u] = hn;
            if (step == TSEQ - 1) {
                out[b * HIDN + u] = hn;                  // hT
                out[NB * HIDN + b * HIDN + u] = cn;      // cT
            }
        }
        __syncthreads();
        buf ^= 1;
    }
}

// ---------------------------------------------------------------------------
extern "C" void kernel_launch(void* const* d_in, const int* in_sizes, int n_in,
                              void* d_out, int out_size, void* d_ws, size_t ws_size,
                              hipStream_t stream) {
    const float* X  = (const float*)d_in[0];   // [32][2048][256]
    const float* Wi = (const float*)d_in[1];   // [256][1024]
    const float* Wh = (const float*)d_in[2];   // [256][1024]
    const float* bv = (const float*)d_in[3];   // [1024]
    const float* h0 = (const float*)d_in[4];   // [32][256]
    const float* c0 = (const float*)d_in[5];   // [32][256]
    float* out = (float*)d_out;

    char* ws = (char*)d_ws;
    uint4* WhpR = (uint4*)(ws);                      // 45*512*16 = 368640 B
    uint4* WhpL = (uint4*)(ws + 368640);             // 19*512*16 = 155648 B
    uint4* Wip  = (uint4*)(ws + (512 << 10));        // 512 KB (unchanged slot)
    unsigned short* XPh = (unsigned short*)(ws + (1 << 20));  // 128 MB

    pack_w<<<256, 256, 0, stream>>>(Wi, Wh, WhpR, WhpL, Wip);
    xproj_gemm<<<2048, 1024, 0, stream>>>(X, Wip, (ushort4*)XPh);
    lstm_rec<<<NB, 512, 0, stream>>>(WhpR, WhpL, XPh, bv, h0, c0, out);
}

// Round 14
// 18047.192 us; speedup vs baseline: 1.8978x; 1.8978x over previous
//
#include <hip/hip_runtime.h>

#define TSEQ 2048
#define NB   32
#define HIDN 256
#define NG   1024   // 4*HID
#define NWR  12     // weight chunks in VGPRs (48 regs)
#define NWL  20     // weight chunks in LDS (80 KB)

typedef _Float16 half_t;
typedef _Float16 half2_t __attribute__((ext_vector_type(2)));

__device__ __forceinline__ float fdot2f16(unsigned int a, unsigned int b, float c) {
#if __has_builtin(__builtin_amdgcn_fdot2)
    return __builtin_amdgcn_fdot2(__builtin_bit_cast(half2_t, a),
                                  __builtin_bit_cast(half2_t, b), c, false);
#else
    half2_t x = __builtin_bit_cast(half2_t, a);
    half2_t y = __builtin_bit_cast(half2_t, b);
    return c + (float)x[0] * (float)y[0] + (float)x[1] * (float)y[1];
#endif
}

__device__ __forceinline__ unsigned int packh2(float lo, float hi) {
    half_t l = (half_t)lo, h = (half_t)hi;
    return (unsigned int)__builtin_bit_cast(unsigned short, l) |
           ((unsigned int)__builtin_bit_cast(unsigned short, h) << 16);
}

__device__ __forceinline__ float fast_exp2(float x) {
#if __has_builtin(__builtin_amdgcn_exp2f)
    return __builtin_amdgcn_exp2f(x);
#else
    return exp2f(x);
#endif
}
__device__ __forceinline__ float fast_rcp(float x) {
#if __has_builtin(__builtin_amdgcn_rcpf)
    return __builtin_amdgcn_rcpf(x);
#else
    return 1.0f / x;
#endif
}
__device__ __forceinline__ float tanh_fast(float x) {
    float e = fast_exp2(x * 2.885390082f);
    return 1.0f - 2.0f * fast_rcp(e + 1.0f);
}

// ---------------------------------------------------------------------------
// K1: pack weights.
//  Wh -> Whp2[(g64*32 + k)*256 + t], g64 in [0,4), k in [0,32), t in [0,256):
//    col = (t&3)*256 + g64*64 + (t>>2)  (gate = t&3, local unit = t>>2)
//    uint4 comp d packs rows (k*8+2d, k*8+2d+1) of col.
//  Wi -> Wip (xproj_gemm layout, unchanged).
// ---------------------------------------------------------------------------
__global__ void pack_w(const float* __restrict__ Wi, const float* __restrict__ Wh,
                       uint4* __restrict__ Whp2, uint4* __restrict__ Wip) {
    int idx = blockIdx.x * 256 + threadIdx.x;   // 0..65535
    if (idx < 32768) {
        int g64 = idx >> 13, k = (idx >> 8) & 31, t = idx & 255;
        int col = (t & 3) * 256 + g64 * 64 + (t >> 2);
        int k0 = k * 8;
        Whp2[idx] = make_uint4(
            packh2(Wh[(k0 + 0) * NG + col], Wh[(k0 + 1) * NG + col]),
            packh2(Wh[(k0 + 2) * NG + col], Wh[(k0 + 3) * NG + col]),
            packh2(Wh[(k0 + 4) * NG + col], Wh[(k0 + 5) * NG + col]),
            packh2(Wh[(k0 + 6) * NG + col], Wh[(k0 + 7) * NG + col]));
    } else {
        int li = idx & 32767;
        int m4 = li >> 10, tt = li & 1023;
        int col = (tt & 3) * 256 + (tt >> 2);
        int k0 = m4 * 8;
        Wip[li] = make_uint4(
            packh2(Wi[(k0 + 0) * NG + col], Wi[(k0 + 1) * NG + col]),
            packh2(Wi[(k0 + 2) * NG + col], Wi[(k0 + 3) * NG + col]),
            packh2(Wi[(k0 + 4) * NG + col], Wi[(k0 + 5) * NG + col]),
            packh2(Wi[(k0 + 6) * NG + col], Wi[(k0 + 7) * NG + col]));
    }
}

// ---------------------------------------------------------------------------
// K2: x_proj GEMM (unchanged): X [65536][256] fp32 @ Wi -> XP ushort4,
// gate-interleaved f16: half index row*1024 + j*4 + g.
// ---------------------------------------------------------------------------
__global__ __launch_bounds__(1024) void xproj_gemm(
    const float* __restrict__ X, const uint4* __restrict__ Wip,
    ushort4* __restrict__ XP)
{
    __shared__ uint4 atile[32][32];
    const int tid = threadIdx.x;
    const long row0 = (long)blockIdx.x * 32;

    {
        int r = tid >> 5, kc = tid & 31;
        const float4* src = (const float4*)(X + (row0 + r) * 256 + kc * 8);
        float4 f0 = src[0], f1 = src[1];
        atile[r][kc] = make_uint4(packh2(f0.x, f0.y), packh2(f0.z, f0.w),
                                  packh2(f1.x, f1.y), packh2(f1.z, f1.w));
    }
    __syncthreads();

    const int j = tid & 255, rq = tid >> 8;
    float acc[8][4];
#pragma unroll
    for (int r = 0; r < 8; ++r)
#pragma unroll
        for (int g = 0; g < 4; ++g) acc[r][g] = 0.f;

    unsigned off = (unsigned)(j * 4);
#pragma unroll 2
    for (int m4 = 0; m4 < 32; ++m4) {
        uint4 w0 = Wip[off + 0];
        uint4 w1 = Wip[off + 1];
        uint4 w2 = Wip[off + 2];
        uint4 w3 = Wip[off + 3];
#pragma unroll
        for (int rr = 0; rr < 8; ++rr) {
            uint4 av = atile[rq * 8 + rr][m4];
            acc[rr][0] = fdot2f16(w0.x, av.x, acc[rr][0]);
            acc[rr][0] = fdot2f16(w0.y, av.y, acc[rr][0]);
            acc[rr][0] = fdot2f16(w0.z, av.z, acc[rr][0]);
            acc[rr][0] = fdot2f16(w0.w, av.w, acc[rr][0]);
            acc[rr][1] = fdot2f16(w1.x, av.x, acc[rr][1]);
            acc[rr][1] = fdot2f16(w1.y, av.y, acc[rr][1]);
            acc[rr][1] = fdot2f16(w1.z, av.z, acc[rr][1]);
            acc[rr][1] = fdot2f16(w1.w, av.w, acc[rr][1]);
            acc[rr][2] = fdot2f16(w2.x, av.x, acc[rr][2]);
            acc[rr][2] = fdot2f16(w2.y, av.y, acc[rr][2]);
            acc[rr][2] = fdot2f16(w2.z, av.z, acc[rr][2]);
            acc[rr][2] = fdot2f16(w2.w, av.w, acc[rr][2]);
            acc[rr][3] = fdot2f16(w3.x, av.x, acc[rr][3]);
            acc[rr][3] = fdot2f16(w3.y, av.y, acc[rr][3]);
            acc[rr][3] = fdot2f16(w3.z, av.z, acc[rr][3]);
            acc[rr][3] = fdot2f16(w3.w, av.w, acc[rr][3]);
        }
        off += 1024;
    }

#pragma unroll
    for (int rr = 0; rr < 8; ++rr) {
        long row = row0 + rq * 8 + rr;
        XP[row * 256 + j] = make_ushort4(
            __builtin_bit_cast(unsigned short, (half_t)acc[rr][0]),
            __builtin_bit_cast(unsigned short, (half_t)acc[rr][1]),
            __builtin_bit_cast(unsigned short, (half_t)acc[rr][2]),
            __builtin_bit_cast(unsigned short, (half_t)acc[rr][3]));
    }
}

// ---------------------------------------------------------------------------
// K3: persistent recurrence, 4 WGs per batch row (128 WGs, 256 thr each).
// Round-13 lesson: the allocator cannot be made to hold >~100 VGPRs of
// weights (remat r5/r9, AGPR r12, spill r13). So shrink per-CU weights to
// LDS scale instead: each WG owns 256 gate-columns (64 units x 4 gates) =
// 128 KB -> 12 chunks VGPR (48 regs; 82 KB LDS forces 1 WG/CU -> 1 wave/SIMD
// -> no occupancy incentive to remat) + 20 chunks LDS. Zero L2 weight stream.
// Cross-WG h exchange per step via TAG-EMBEDDED u32 atomics:
//   atom = (step+1)<<16 | f16(h)   (release store / acquire spin-load, agent)
// parity-double-buffered; data inside the atomic word -> coherence by
// atomic semantics alone (G16/m20). atoms memset to 0 each launch.
// Co-residency: 128 WGs <= 256 CUs, sole kernel -> no deadlock.
// Block map: row's 4 WGs share blockIdx%8 -> same XCD L2 for the exchange.
// ---------------------------------------------------------------------------
__global__ __launch_bounds__(256) void lstm_rec(
    const uint4* __restrict__ Whp2, const unsigned short* __restrict__ XPh,
    const float* __restrict__ bias, const float* __restrict__ h0,
    const float* __restrict__ c0, unsigned int* __restrict__ atoms,
    float* __restrict__ out)
{
    __shared__ __align__(16) uint4 wlds[NWL][256];        // 80 KB
    __shared__ __align__(16) unsigned short hbuf[256];    // 512 B

    const int t    = threadIdx.x;
    const int i    = blockIdx.x;              // 0..127
    const int xcd  = i & 7, jj = i >> 3;
    const int g64  = jj & 3;                  // column-group 0..3
    const int b    = xcd + 8 * (jj >> 2);     // batch row 0..31
    const int gate = t & 3, v = t >> 2;
    const int uu   = g64 * 64 + v;            // this quad's unit
    const int col  = gate * 256 + uu;

    const unsigned base = (unsigned)g64 * 8192;
    uint4 wr[NWR];
#pragma unroll
    for (int r = 0; r < NWR; ++r) wr[r] = Whp2[base + r * 256 + t];
#pragma unroll
    for (int c = 0; c < NWL; ++c) wlds[c][t] = Whp2[base + (NWR + c) * 256 + t];

    const float bc = bias[col];
    float c_state  = c0[b * HIDN + uu];       // replicated across the quad
    hbuf[t] = __builtin_bit_cast(unsigned short, (half_t)h0[b * HIDN + t]);

    const unsigned short* xp = XPh + (long)b * TSEQ * NG + g64 * 256 + t;
    float* ys = out + 2 * NB * HIDN + (long)b * TSEQ * HIDN;
    unsigned int* atrow = atoms + b * 2 * 256;
    const int uur = (t < g64 * 64) ? t : t + 64;   // remote unit (t < 192)
    __syncthreads();

    for (int step = 0; step < TSEQ; ++step) {
        float xpf = (float)__builtin_bit_cast(half_t, xp[(long)step * NG]);

        const uint4* hv4 = (const uint4*)hbuf;
        float z0 = 0.f, z1 = 0.f, z2 = 0.f, z3 = 0.f;
#pragma unroll
        for (int k = 0; k < 32; k += 4) {
            uint4 w0 = (k + 0 < NWR) ? wr[k + 0] : wlds[k + 0 - NWR][t];
            uint4 w1 = (k + 1 < NWR) ? wr[k + 1] : wlds[k + 1 - NWR][t];
            uint4 w2 = (k + 2 < NWR) ? wr[k + 2] : wlds[k + 2 - NWR][t];
            uint4 w3 = (k + 3 < NWR) ? wr[k + 3] : wlds[k + 3 - NWR][t];
            uint4 h0v = hv4[k + 0], h1v = hv4[k + 1];
            uint4 h2v = hv4[k + 2], h3v = hv4[k + 3];
            z0 = fdot2f16(w0.x, h0v.x, z0); z0 = fdot2f16(w0.y, h0v.y, z0);
            z0 = fdot2f16(w0.z, h0v.z, z0); z0 = fdot2f16(w0.w, h0v.w, z0);
            z1 = fdot2f16(w1.x, h1v.x, z1); z1 = fdot2f16(w1.y, h1v.y, z1);
            z1 = fdot2f16(w1.z, h1v.z, z1); z1 = fdot2f16(w1.w, h1v.w, z1);
            z2 = fdot2f16(w2.x, h2v.x, z2); z2 = fdot2f16(w2.y, h2v.y, z2);
            z2 = fdot2f16(w2.z, h2v.z, z2); z2 = fdot2f16(w2.w, h2v.w, z2);
            z3 = fdot2f16(w3.x, h3v.x, z3); z3 = fdot2f16(w3.y, h3v.y, z3);
            z3 = fdot2f16(w3.z, h3v.z, z3); z3 = fdot2f16(w3.w, h3v.w, z3);
        }
        float z = (z0 + z1) + (z2 + z3) + xpf + bc;

        // activation: gate 2 tanh, others sigmoid (shared exp2 path)
        float sc = (gate == 2) ? 2.885390082f : -1.442695041f;
        float e  = fast_exp2(z * sc);
        float rr = fast_rcp(1.0f + e);
        float a  = (gate == 2) ? 1.0f - 2.0f * rr : rr;

        // in-quad all-gather of the 4 gate activations
        float b1 = __shfl_xor(a, 1);
        float b2 = __shfl_xor(a, 2);
        float b3 = __shfl_xor(b1, 2);
        float gi = (gate == 0) ? a : (gate == 1) ? b1 : (gate == 2) ? b2 : b3;
        float gf = (gate == 1) ? a : (gate == 0) ? b1 : (gate == 3) ? b2 : b3;
        float gg = (gate == 2) ? a : (gate == 3) ? b1 : (gate == 0) ? b2 : b3;
        float go = (gate == 3) ? a : (gate == 2) ? b1 : (gate == 1) ? b2 : b3;

        float cn = gf * c_state + gi * gg;
        float hn = go * tanh_fast(cn);
        c_state = cn;
        unsigned short h16 = __builtin_bit_cast(unsigned short, (half_t)hn);

        __syncthreads();   // everyone done reading hbuf for this step

        const int p = (step + 1) & 1;
        const unsigned tag = (unsigned)(step + 1);
        if (gate == 0) {
            __hip_atomic_store(&atrow[p * 256 + uu], (tag << 16) | h16,
                               __ATOMIC_RELEASE, __HIP_MEMORY_SCOPE_AGENT);
            hbuf[uu] = h16;
            ys[(long)step * HIDN + uu] = hn;
            if (step == TSEQ - 1) {
                out[b * HIDN + uu] = hn;                  // hT
                out[NB * HIDN + b * HIDN + uu] = cn;      // cT
            }
        }
        if (t < 192) {
            unsigned got;
            do {
                got = __hip_atomic_load(&atrow[p * 256 + uur],
                                        __ATOMIC_ACQUIRE, __HIP_MEMORY_SCOPE_AGENT);
            } while ((got >> 16) != tag);
            hbuf[uur] = (unsigned short)(got & 0xffffu);
        }
        __syncthreads();
    }
}

// ---------------------------------------------------------------------------
extern "C" void kernel_launch(void* const* d_in, const int* in_sizes, int n_in,
                              void* d_out, int out_size, void* d_ws, size_t ws_size,
                              hipStream_t stream) {
    const float* X  = (const float*)d_in[0];   // [32][2048][256]
    const float* Wi = (const float*)d_in[1];   // [256][1024]
    const float* Wh = (const float*)d_in[2];   // [256][1024]
    const float* bv = (const float*)d_in[3];   // [1024]
    const float* h0 = (const float*)d_in[4];   // [32][256]
    const float* c0 = (const float*)d_in[5];   // [32][256]
    float* out = (float*)d_out;

    char* ws = (char*)d_ws;
    uint4* Whp2 = (uint4*)(ws);                      // 512 KB
    uint4* Wip  = (uint4*)(ws + (512 << 10));        // 512 KB
    unsigned short* XPh = (unsigned short*)(ws + (1 << 20));  // 128 MB
    // atoms reuse the Wip region (Wip is dead after xproj_gemm): 64 KB
    unsigned int* atoms = (unsigned int*)(ws + (512 << 10));

    pack_w<<<256, 256, 0, stream>>>(Wi, Wh, Whp2, Wip);
    xproj_gemm<<<2048, 1024, 0, stream>>>(X, Wip, (ushort4*)XPh);
    hipMemsetAsync(atoms, 0, NB * 2 * 256 * sizeof(unsigned int), stream);
    lstm_rec<<<128, 256, 0, stream>>>(Whp2, XPh, bv, h0, c0, atoms, out);
}